// Round 1
// baseline (670.791 us; speedup 1.0000x reference)
//
#include <hip/hip_runtime.h>
#include <math.h>

// Problem constants
#define HID   4096
#define SLOTS 8
#define HEADS 8
#define BD    512
#define HD    64
#define BB    4
#define SS    4096
#define R64   64          // HEADS*SLOTS rows; r = h*8 + n

// Workspace layout (floats):
//   Q    [8][512]                4096
//   QW   [64][4096]            262144   (pre-scaled by 1/8)
//   sp   [4][4][64][4096]     4194304   (partial scores; reused as partial ctx)
//   attn [4][64][4096]        1048576
//   ctx  [4][64][4096]        1048576
//   out  [4][8][512]            16384
// total ~6.57M floats ~= 26.3 MB of d_ws

// ---- 1: Q = ms @ Wq^T  (8x512). One wave per output element.
__global__ void q_kernel(const float* __restrict__ ms, const float* __restrict__ Wq,
                         float* __restrict__ Q) {
  int w = (blockIdx.x * blockDim.x + threadIdx.x) >> 6;
  int lane = threadIdx.x & 63;
  if (w >= SLOTS * BD) return;
  int n = w >> 9, o = w & (BD - 1);
  const float* a = ms + n * HID;
  const float* b = Wq + (size_t)o * HID;
  float acc = 0.f;
  for (int i = lane; i < HID; i += 64) acc = fmaf(a[i], b[i], acc);
  #pragma unroll
  for (int off = 32; off; off >>= 1) acc += __shfl_down(acc, off, 64);
  if (lane == 0) Q[w] = acc;
}

// ---- 2: QW[r][i] = 0.125 * sum_d Q[n][h*64+d] * Wk[h*64+d][i],  r = h*8+n
__global__ void qw_kernel(const float* __restrict__ Q, const float* __restrict__ Wk,
                          float* __restrict__ QW) {
  int idx = blockIdx.x * blockDim.x + threadIdx.x;   // 64*4096
  int r = idx >> 12, i = idx & (HID - 1);
  int h = r >> 3, n = r & 7;
  const float* q  = Q + n * BD + h * HD;
  const float* wk = Wk + (size_t)(h * HD) * HID + i;
  float acc = 0.f;
  #pragma unroll 8
  for (int d = 0; d < HD; ++d) acc = fmaf(q[d], wk[(size_t)d * HID], acc);
  QW[idx] = acc * 0.125f;
}

// ---- 3: partial scores  sp[ks][b][r][s] = sum_{k in 1024-slice} hs[b][s][k]*QW[r][k]
// grid (64 s-tiles, 4 k-slices, 4 b), 256 thr, 64x64 tile, 4x4 per thread.
__global__ __launch_bounds__(256) void scores_kernel(const float* __restrict__ hs,
                                                     const float* __restrict__ QW,
                                                     float* __restrict__ sp) {
  __shared__ float As[64][68];  // [k][s]  (stride 68 floats = 272B: 16B aligned rows)
  __shared__ float Bs[64][68];  // [k][r]
  int stile = blockIdx.x, ks = blockIdx.y, b = blockIdx.z;
  int tid = threadIdx.x;
  int tx = tid & 15, ty = tid >> 4;
  const float* hsb = hs + ((size_t)b * SS + stile * 64) * HID;
  float acc[4][4] = {};   // [si][ri]
  int kk = (tid & 15) * 4, row = tid >> 4;
  for (int k0 = ks * 1024; k0 < ks * 1024 + 1024; k0 += 64) {
    #pragma unroll
    for (int j = 0; j < 4; ++j) {
      int s = row + 16 * j;
      float4 v = *(const float4*)(hsb + (size_t)s * HID + k0 + kk);
      As[kk + 0][s] = v.x; As[kk + 1][s] = v.y; As[kk + 2][s] = v.z; As[kk + 3][s] = v.w;
      float4 u = *(const float4*)(QW + (size_t)s * HID + k0 + kk);  // s doubles as r row
      Bs[kk + 0][s] = u.x; Bs[kk + 1][s] = u.y; Bs[kk + 2][s] = u.z; Bs[kk + 3][s] = u.w;
    }
    __syncthreads();
    #pragma unroll 8
    for (int k = 0; k < 64; ++k) {
      float4 a  = *(const float4*)&As[k][ty * 4];
      float4 bq = *(const float4*)&Bs[k][tx * 4];
      float av[4] = {a.x, a.y, a.z, a.w};
      float bv[4] = {bq.x, bq.y, bq.z, bq.w};
      #pragma unroll
      for (int si = 0; si < 4; ++si)
        #pragma unroll
        for (int ri = 0; ri < 4; ++ri)
          acc[si][ri] = fmaf(av[si], bv[ri], acc[si][ri]);
    }
    __syncthreads();
  }
  size_t base = (((size_t)ks * BB + b) * R64) * SS + stile * 64;
  #pragma unroll
  for (int ri = 0; ri < 4; ++ri) {
    float4 v = make_float4(acc[0][ri], acc[1][ri], acc[2][ri], acc[3][ri]);
    int r = tx * 4 + ri;
    *(float4*)(sp + base + (size_t)r * SS + ty * 4) = v;
  }
}

// ---- 4: softmax over s per (b,r), summing 4 K-partials, applying mask.
__global__ __launch_bounds__(256) void softmax_kernel(const float* __restrict__ sp,
                                                      const int* __restrict__ mask,
                                                      float* __restrict__ attn) {
  int br = blockIdx.x;            // b*64 + r
  int b = br >> 6;
  int tid = threadIdx.x;
  const int* mrow = mask + b * SS;
  float vals[16];
  float mx = -INFINITY;
  #pragma unroll
  for (int j = 0; j < 16; ++j) {
    int s = tid + j * 256;
    float v = sp[(size_t)(0 * 256 + br) * SS + s] + sp[(size_t)(1 * 256 + br) * SS + s]
            + sp[(size_t)(2 * 256 + br) * SS + s] + sp[(size_t)(3 * 256 + br) * SS + s];
    if (mrow[s] == 0) v = -INFINITY;
    vals[j] = v;
    mx = fmaxf(mx, v);
  }
  __shared__ float redm[4], reds[4];
  #pragma unroll
  for (int off = 32; off; off >>= 1) mx = fmaxf(mx, __shfl_down(mx, off, 64));
  if ((tid & 63) == 0) redm[tid >> 6] = mx;
  __syncthreads();
  mx = fmaxf(fmaxf(redm[0], redm[1]), fmaxf(redm[2], redm[3]));
  float sum = 0.f;
  #pragma unroll
  for (int j = 0; j < 16; ++j) { vals[j] = expf(vals[j] - mx); sum += vals[j]; }
  #pragma unroll
  for (int off = 32; off; off >>= 1) sum += __shfl_down(sum, off, 64);
  if ((tid & 63) == 0) reds[tid >> 6] = sum;
  __syncthreads();
  sum = reds[0] + reds[1] + reds[2] + reds[3];
  float inv = 1.f / sum;
  #pragma unroll
  for (int j = 0; j < 16; ++j)
    attn[(size_t)br * SS + tid + j * 256] = vals[j] * inv;
}

// ---- 5: partial ctx  cp[ks][b][r][i] = sum_{s in 1024-slice} attn[b][r][s]*hs[b][s][i]
__global__ __launch_bounds__(256) void ctx_kernel(const float* __restrict__ attn,
                                                  const float* __restrict__ hs,
                                                  float* __restrict__ cp) {
  __shared__ float As[64][68];  // [sk][r]
  __shared__ float Bs[64][68];  // [sk][i]
  int itile = blockIdx.x, ks = blockIdx.y, b = blockIdx.z;
  int tid = threadIdx.x;
  int tx = tid & 15, ty = tid >> 4;
  const float* ab = attn + (size_t)b * R64 * SS;
  const float* hb = hs + (size_t)b * SS * HID + itile * 64;
  float acc[4][4] = {};   // [ri][ii]
  int kk = (tid & 15) * 4, row = tid >> 4;
  for (int s0 = ks * 1024; s0 < ks * 1024 + 1024; s0 += 64) {
    #pragma unroll
    for (int j = 0; j < 4; ++j) {
      int r = row + 16 * j;
      float4 u = *(const float4*)(ab + (size_t)r * SS + s0 + kk);
      As[kk + 0][r] = u.x; As[kk + 1][r] = u.y; As[kk + 2][r] = u.z; As[kk + 3][r] = u.w;
      int sk = r;
      float4 v = *(const float4*)(hb + (size_t)(s0 + sk) * HID + kk);
      *(float4*)&Bs[sk][kk] = v;   // aligned: row stride 272B, kk*4 multiple of 16
    }
    __syncthreads();
    #pragma unroll 8
    for (int k = 0; k < 64; ++k) {
      float4 a  = *(const float4*)&As[k][ty * 4];
      float4 bq = *(const float4*)&Bs[k][tx * 4];
      float av[4] = {a.x, a.y, a.z, a.w};
      float bv[4] = {bq.x, bq.y, bq.z, bq.w};
      #pragma unroll
      for (int ri = 0; ri < 4; ++ri)
        #pragma unroll
        for (int ii = 0; ii < 4; ++ii)
          acc[ri][ii] = fmaf(av[ri], bv[ii], acc[ri][ii]);
    }
    __syncthreads();
  }
  size_t base = (((size_t)ks * BB + b) * R64) * HID + itile * 64;
  #pragma unroll
  for (int ri = 0; ri < 4; ++ri) {
    float4 v = make_float4(acc[ri][0], acc[ri][1], acc[ri][2], acc[ri][3]);
    int r = ty * 4 + ri;
    *(float4*)(cp + base + (size_t)r * HID + tx * 4) = v;
  }
}

// ---- 6: reduce ctx partials
__global__ void ctx_reduce_kernel(const float* __restrict__ cp, float* __restrict__ ctx) {
  int idx = blockIdx.x * blockDim.x + threadIdx.x;   // 1M
  const size_t n = (size_t)BB * R64 * HID;
  ctx[idx] = cp[idx] + cp[idx + n] + cp[idx + 2 * n] + cp[idx + 3 * n];
}

// ---- 7: out[b][n][h*64+d] = sum_i ctx[b][h*8+n][i] * Wv[h*64+d][i]
__global__ void out_kernel(const float* __restrict__ ctx, const float* __restrict__ Wv,
                           float* __restrict__ out) {
  int w = (blockIdx.x * blockDim.x + threadIdx.x) >> 6;
  int lane = threadIdx.x & 63;
  if (w >= BB * SLOTS * BD) return;   // 16384
  int b = w >> 12, n = (w >> 9) & 7, hd = w & 511, h = hd >> 6;
  const float* c  = ctx + ((size_t)b * R64 + h * 8 + n) * HID;
  const float* wv = Wv + (size_t)hd * HID;
  float acc = 0.f;
  for (int i = lane; i < HID; i += 64) acc = fmaf(c[i], wv[i], acc);
  #pragma unroll
  for (int off = 32; off; off >>= 1) acc += __shfl_down(acc, off, 64);
  if (lane == 0) out[w] = acc;
}

// ---- 8: y[b][n][o] = sum_d out[b][n][d] * Wo[o][d]
__global__ void final_kernel(const float* __restrict__ out, const float* __restrict__ Wo,
                             float* __restrict__ y) {
  int w = (blockIdx.x * blockDim.x + threadIdx.x) >> 6;
  int lane = threadIdx.x & 63;
  if (w >= BB * SLOTS * HID) return;  // 131072
  int bn = w >> 12, o = w & 4095;
  const float* orow = out + bn * BD;
  const float* wo = Wo + (size_t)o * BD;
  float acc = 0.f;
  #pragma unroll
  for (int d = lane; d < BD; d += 64) acc = fmaf(orow[d], wo[d], acc);
  #pragma unroll
  for (int off = 32; off; off >>= 1) acc += __shfl_down(acc, off, 64);
  if (lane == 0) y[w] = acc;
}

extern "C" void kernel_launch(void* const* d_in, const int* in_sizes, int n_in,
                              void* d_out, int out_size, void* d_ws, size_t ws_size,
                              hipStream_t stream) {
  const float* hs   = (const float*)d_in[0];
  const int*   mask = (const int*)d_in[1];
  const float* ms   = (const float*)d_in[2];
  const float* Wq   = (const float*)d_in[3];
  const float* Wk   = (const float*)d_in[4];
  const float* Wv   = (const float*)d_in[5];
  const float* Wo   = (const float*)d_in[6];

  float* ws   = (float*)d_ws;           // requires ~26.3 MB of workspace
  float* Q    = ws;                     // 4096
  float* QW   = Q + 4096;               // 262144
  float* sp   = QW + 262144;            // 4194304 (partial scores / partial ctx)
  float* attn = sp + 4194304;           // 1048576
  float* ctx  = attn + 1048576;         // 1048576
  float* out  = ctx + 1048576;          // 16384

  q_kernel<<<dim3((SLOTS * BD * 64) / 256), 256, 0, stream>>>(ms, Wq, Q);
  qw_kernel<<<dim3((R64 * HID) / 256), 256, 0, stream>>>(Q, Wk, QW);
  scores_kernel<<<dim3(64, 4, 4), 256, 0, stream>>>(hs, QW, sp);
  softmax_kernel<<<dim3(BB * R64), 256, 0, stream>>>(sp, mask, attn);
  float* cp = sp;  // reuse partial-score buffer for partial ctx
  ctx_kernel<<<dim3(64, 4, 4), 256, 0, stream>>>(attn, hs, cp);
  ctx_reduce_kernel<<<dim3(4096), 256, 0, stream>>>(cp, ctx);
  out_kernel<<<dim3(4096), 256, 0, stream>>>(ctx, Wv, out);
  final_kernel<<<dim3(32768), 256, 0, stream>>>(out, Wo, (float*)d_out);
}

// Round 2
// 580.255 us; speedup vs baseline: 1.1560x; 1.1560x over previous
//
#include <hip/hip_runtime.h>
#include <math.h>

// Problem constants
#define HID   4096
#define SLOTS 8
#define HEADS 8
#define BD    512
#define HD    64
#define BB    4
#define SS    4096
#define R64   64          // HEADS*SLOTS rows; r = h*8 + n
#define LSTR  72          // LDS row stride in bf16 elems (144 B: 16B-aligned rows, low-conflict)

typedef __attribute__((ext_vector_type(8))) short bf16x8;
typedef __attribute__((ext_vector_type(4))) float f32x4;

// fp32 -> bf16 bits, round-to-nearest-even (inputs finite)
__device__ __forceinline__ unsigned short f2bf(float x) {
  unsigned int u = __builtin_bit_cast(unsigned int, x);
  return (unsigned short)((u + 0x7fffu + ((u >> 16) & 1u)) >> 16);
}

// ---- 1: Q = ms @ Wq^T  (8x512). One wave per output element.
__global__ void q_kernel(const float* __restrict__ ms, const float* __restrict__ Wq,
                         float* __restrict__ Q) {
  int w = (blockIdx.x * blockDim.x + threadIdx.x) >> 6;
  int lane = threadIdx.x & 63;
  if (w >= SLOTS * BD) return;
  int n = w >> 9, o = w & (BD - 1);
  const float* a = ms + n * HID;
  const float* b = Wq + (size_t)o * HID;
  float acc = 0.f;
  for (int i = lane; i < HID; i += 64) acc = fmaf(a[i], b[i], acc);
  #pragma unroll
  for (int off = 32; off; off >>= 1) acc += __shfl_down(acc, off, 64);
  if (lane == 0) Q[w] = acc;
}

// ---- 2: QW[r][i] = 0.125 * sum_d Q[n][h*64+d] * Wk[h*64+d][i],  r = h*8+n  (bf16 out)
__global__ void qw_kernel(const float* __restrict__ Q, const float* __restrict__ Wk,
                          unsigned short* __restrict__ QW) {
  int idx = blockIdx.x * blockDim.x + threadIdx.x;   // 64*4096
  int r = idx >> 12, i = idx & (HID - 1);
  int h = r >> 3, n = r & 7;
  const float* q  = Q + n * BD + h * HD;
  const float* wk = Wk + (size_t)(h * HD) * HID + i;
  float acc = 0.f;
  #pragma unroll 8
  for (int d = 0; d < HD; ++d) acc = fmaf(q[d], wk[(size_t)d * HID], acc);
  QW[idx] = f2bf(acc * 0.125f);
}

// ---- 3: scores sp[b][r][s] = sum_k hs[b][s][k]*QW[r][k]  via bf16 MFMA
// grid (64 s-tiles, 4 b), 256 thr. Tile M=64(s) x N=64(r), K=4096.
// Wave w: n-tile w (16 r), 4 m-tiles. Verified 16x16x32 layouts:
//   A[m=lane&15][k=quad*8+j] ; B from [n][k] rows identically ; C: col=lane&15,row=quad*4+reg
__global__ __launch_bounds__(256) void scores_mfma(const float* __restrict__ hs,
                                                   const unsigned short* __restrict__ QW,
                                                   float* __restrict__ sp) {
  __shared__ unsigned short As[64 * LSTR];  // [s][k]
  __shared__ unsigned short Bs[64 * LSTR];  // [r][k]
  const int stile = blockIdx.x, b = blockIdx.y;
  const int tid = threadIdx.x;
  const int wv = tid >> 6, lane = tid & 63;
  const int quad = lane >> 4, l16 = lane & 15;
  // staging map: thread -> (row 0..63, 16 contiguous k at kc)
  const int srow = tid >> 2, kc = (tid & 3) << 4;
  const float* hsp = hs + ((size_t)(b * SS + stile * 64 + srow)) * HID + kc;
  const unsigned short* qwp = QW + (size_t)srow * HID + kc;

  f32x4 acc[4] = {};
  float4 fa0 = *(const float4*)(hsp + 0);
  float4 fa1 = *(const float4*)(hsp + 4);
  float4 fa2 = *(const float4*)(hsp + 8);
  float4 fa3 = *(const float4*)(hsp + 12);
  uint4 qb0 = *(const uint4*)(qwp);
  uint4 qb1 = *(const uint4*)(qwp + 8);

  for (int c = 0; c < 64; ++c) {
    __syncthreads();
    union { unsigned short us[16]; uint4 q[2]; } u;
    float f[16] = {fa0.x, fa0.y, fa0.z, fa0.w, fa1.x, fa1.y, fa1.z, fa1.w,
                   fa2.x, fa2.y, fa2.z, fa2.w, fa3.x, fa3.y, fa3.z, fa3.w};
    #pragma unroll
    for (int j = 0; j < 16; ++j) u.us[j] = f2bf(f[j]);
    *(uint4*)&As[srow * LSTR + kc]     = u.q[0];
    *(uint4*)&As[srow * LSTR + kc + 8] = u.q[1];
    *(uint4*)&Bs[srow * LSTR + kc]     = qb0;
    *(uint4*)&Bs[srow * LSTR + kc + 8] = qb1;
    __syncthreads();
    if (c < 63) {
      const float* p = hsp + (size_t)(c + 1) * 64;
      fa0 = *(const float4*)(p + 0);
      fa1 = *(const float4*)(p + 4);
      fa2 = *(const float4*)(p + 8);
      fa3 = *(const float4*)(p + 12);
      const unsigned short* q = qwp + (size_t)(c + 1) * 64;
      qb0 = *(const uint4*)(q);
      qb1 = *(const uint4*)(q + 8);
    }
    #pragma unroll
    for (int ks = 0; ks < 2; ++ks) {
      bf16x8 bfrag = *(const bf16x8*)&Bs[(wv * 16 + l16) * LSTR + ks * 32 + quad * 8];
      #pragma unroll
      for (int mt = 0; mt < 4; ++mt) {
        bf16x8 afrag = *(const bf16x8*)&As[(mt * 16 + l16) * LSTR + ks * 32 + quad * 8];
        acc[mt] = __builtin_amdgcn_mfma_f32_16x16x32_bf16(afrag, bfrag, acc[mt], 0, 0, 0);
      }
    }
  }
  const int r = wv * 16 + l16;
  #pragma unroll
  for (int mt = 0; mt < 4; ++mt) {
    int s = stile * 64 + mt * 16 + quad * 4;
    float4 v = make_float4(acc[mt][0], acc[mt][1], acc[mt][2], acc[mt][3]);
    *(float4*)(sp + ((size_t)(b * R64 + r)) * SS + s) = v;
  }
}

// ---- 4: softmax over s per (b,r), mask applied; bf16 attn out.
__global__ __launch_bounds__(256) void softmax_kernel(const float* __restrict__ sp,
                                                      const int* __restrict__ mask,
                                                      unsigned short* __restrict__ attn) {
  int br = blockIdx.x;            // b*64 + r
  int b = br >> 6;
  int tid = threadIdx.x;
  const float* row = sp + (size_t)br * SS;
  const int* mrow = mask + b * SS;
  float vals[16];
  float mx = -INFINITY;
  #pragma unroll
  for (int j = 0; j < 16; ++j) {
    int s = tid + j * 256;
    float v = row[s];
    if (mrow[s] == 0) v = -INFINITY;
    vals[j] = v;
    mx = fmaxf(mx, v);
  }
  __shared__ float redm[4], reds[4];
  #pragma unroll
  for (int off = 32; off; off >>= 1) mx = fmaxf(mx, __shfl_down(mx, off, 64));
  if ((tid & 63) == 0) redm[tid >> 6] = mx;
  __syncthreads();
  mx = fmaxf(fmaxf(redm[0], redm[1]), fmaxf(redm[2], redm[3]));
  float sum = 0.f;
  #pragma unroll
  for (int j = 0; j < 16; ++j) { vals[j] = expf(vals[j] - mx); sum += vals[j]; }
  #pragma unroll
  for (int off = 32; off; off >>= 1) sum += __shfl_down(sum, off, 64);
  if ((tid & 63) == 0) reds[tid >> 6] = sum;
  __syncthreads();
  sum = reds[0] + reds[1] + reds[2] + reds[3];
  float inv = 1.f / sum;
  #pragma unroll
  for (int j = 0; j < 16; ++j)
    attn[(size_t)br * SS + tid + j * 256] = f2bf(vals[j] * inv);
}

// ---- 5: ctx[b][r][i] = sum_s attn[b][r][s]*hs[b][s][i]  via bf16 MFMA
// grid (64 i-tiles, 4 b). Tile M=64(r) x N=64(i), K=4096(s).
// B operand needs [n=i][k=s] rows -> transpose hs chunk into LDS with packed b32 writes.
__global__ __launch_bounds__(256) void ctx_mfma(const unsigned short* __restrict__ attn,
                                                const float* __restrict__ hs,
                                                float* __restrict__ ctx) {
  __shared__ unsigned short As[64 * LSTR];  // [r][s]
  __shared__ unsigned short Bs[64 * LSTR];  // [i][s]  (transposed hs tile)
  const int itile = blockIdx.x, b = blockIdx.y;
  const int tid = threadIdx.x;
  const int wv = tid >> 6, lane = tid & 63;
  const int quad = lane >> 4, l16 = lane & 15;
  // A staging: thread -> (r row 0..63, 16 contiguous s at asc)
  const int arow = tid >> 2, asc = (tid & 3) << 4;
  const unsigned short* ap = attn + ((size_t)(b * R64 + arow)) * SS + asc;
  // B staging: thread -> s-pair p (rows 2p,2p+1), i-group g (8 cols at g*8)
  const int p = tid & 31, g = tid >> 5;
  const float* bp0 = hs + ((size_t)(b * SS + 2 * p)) * HID + itile * 64 + g * 8;
  const float* bp1 = bp0 + HID;

  f32x4 acc[4] = {};
  uint4 aa0 = *(const uint4*)(ap);
  uint4 aa1 = *(const uint4*)(ap + 8);
  float4 hb00 = *(const float4*)(bp0);
  float4 hb01 = *(const float4*)(bp0 + 4);
  float4 hb10 = *(const float4*)(bp1);
  float4 hb11 = *(const float4*)(bp1 + 4);

  for (int c = 0; c < 64; ++c) {
    __syncthreads();
    *(uint4*)&As[arow * LSTR + asc]     = aa0;
    *(uint4*)&As[arow * LSTR + asc + 8] = aa1;
    {
      float lo[8] = {hb00.x, hb00.y, hb00.z, hb00.w, hb01.x, hb01.y, hb01.z, hb01.w};
      float hi[8] = {hb10.x, hb10.y, hb10.z, hb10.w, hb11.x, hb11.y, hb11.z, hb11.w};
      #pragma unroll
      for (int j = 0; j < 8; ++j) {
        unsigned int v = (unsigned int)f2bf(lo[j]) | ((unsigned int)f2bf(hi[j]) << 16);
        ((unsigned int*)Bs)[(g * 8 + j) * (LSTR / 2) + p] = v;  // Bs[i][2p..2p+1]
      }
    }
    __syncthreads();
    if (c < 63) {
      const unsigned short* an = ap + (size_t)(c + 1) * 64;
      aa0 = *(const uint4*)(an);
      aa1 = *(const uint4*)(an + 8);
      const float* bn0 = bp0 + (size_t)(c + 1) * 64 * HID;
      const float* bn1 = bn0 + HID;
      hb00 = *(const float4*)(bn0);
      hb01 = *(const float4*)(bn0 + 4);
      hb10 = *(const float4*)(bn1);
      hb11 = *(const float4*)(bn1 + 4);
    }
    #pragma unroll
    for (int ks = 0; ks < 2; ++ks) {
      bf16x8 bfrag = *(const bf16x8*)&Bs[(wv * 16 + l16) * LSTR + ks * 32 + quad * 8];
      #pragma unroll
      for (int mt = 0; mt < 4; ++mt) {
        bf16x8 afrag = *(const bf16x8*)&As[(mt * 16 + l16) * LSTR + ks * 32 + quad * 8];
        acc[mt] = __builtin_amdgcn_mfma_f32_16x16x32_bf16(afrag, bfrag, acc[mt], 0, 0, 0);
      }
    }
  }
  const int i = itile * 64 + wv * 16 + l16;
  #pragma unroll
  for (int mt = 0; mt < 4; ++mt) {
    int r0 = mt * 16 + quad * 4;
    #pragma unroll
    for (int j = 0; j < 4; ++j)
      ctx[((size_t)(b * R64 + r0 + j)) * HID + i] = acc[mt][j];
  }
}

// ---- 6: out[b][n][h*64+d] = sum_i ctx[b][h*8+n][i] * Wv[h*64+d][i]
__global__ void out_kernel(const float* __restrict__ ctx, const float* __restrict__ Wv,
                           float* __restrict__ out) {
  int w = (blockIdx.x * blockDim.x + threadIdx.x) >> 6;
  int lane = threadIdx.x & 63;
  if (w >= BB * SLOTS * BD) return;   // 16384
  int b = w >> 12, n = (w >> 9) & 7, hd = w & 511, h = hd >> 6;
  const float* c  = ctx + ((size_t)b * R64 + h * 8 + n) * HID;
  const float* wv = Wv + (size_t)hd * HID;
  float acc = 0.f;
  for (int i = lane; i < HID; i += 64) acc = fmaf(c[i], wv[i], acc);
  #pragma unroll
  for (int off = 32; off; off >>= 1) acc += __shfl_down(acc, off, 64);
  if (lane == 0) out[w] = acc;
}

// ---- 7: y[b][n][o] = sum_d out[b][n][d] * Wo[o][d]
__global__ void final_kernel(const float* __restrict__ out, const float* __restrict__ Wo,
                             float* __restrict__ y) {
  int w = (blockIdx.x * blockDim.x + threadIdx.x) >> 6;
  int lane = threadIdx.x & 63;
  if (w >= BB * SLOTS * HID) return;  // 131072
  int bn = w >> 12, o = w & 4095;
  const float* orow = out + bn * BD;
  const float* wo = Wo + (size_t)o * BD;
  float acc = 0.f;
  #pragma unroll
  for (int d = lane; d < BD; d += 64) acc = fmaf(orow[d], wo[d], acc);
  #pragma unroll
  for (int off = 32; off; off >>= 1) acc += __shfl_down(acc, off, 64);
  if (lane == 0) y[w] = acc;
}

extern "C" void kernel_launch(void* const* d_in, const int* in_sizes, int n_in,
                              void* d_out, int out_size, void* d_ws, size_t ws_size,
                              hipStream_t stream) {
  const float* hs   = (const float*)d_in[0];
  const int*   mask = (const int*)d_in[1];
  const float* ms   = (const float*)d_in[2];
  const float* Wq   = (const float*)d_in[3];
  const float* Wk   = (const float*)d_in[4];
  const float* Wv   = (const float*)d_in[5];
  const float* Wo   = (const float*)d_in[6];

  // Workspace layout (~10.6 MB)
  char* ws = (char*)d_ws;
  float*          Q    = (float*)ws;                    ws += 4096 * 4;           // 16 KB
  unsigned short* QW   = (unsigned short*)ws;           ws += R64 * HID * 2;      // 512 KB
  float*          sp   = (float*)ws;                    ws += (size_t)BB * R64 * SS * 4;   // 4 MB
  unsigned short* attn = (unsigned short*)ws;           ws += (size_t)BB * R64 * SS * 2;   // 2 MB
  float*          ctx  = (float*)ws;                    ws += (size_t)BB * R64 * HID * 4;  // 4 MB
  float*          out  = (float*)ws;                                              // 64 KB

  q_kernel<<<dim3((SLOTS * BD * 64) / 256), 256, 0, stream>>>(ms, Wq, Q);
  qw_kernel<<<dim3((R64 * HID) / 256), 256, 0, stream>>>(Q, Wk, QW);
  scores_mfma<<<dim3(64, 4), 256, 0, stream>>>(hs, QW, sp);
  softmax_kernel<<<dim3(BB * R64), 256, 0, stream>>>(sp, mask, attn);
  ctx_mfma<<<dim3(64, 4), 256, 0, stream>>>(attn, hs, ctx);
  out_kernel<<<dim3(4096), 256, 0, stream>>>(ctx, Wv, out);
  final_kernel<<<dim3(32768), 256, 0, stream>>>(out, Wo, (float*)d_out);
}